// Round 20
// baseline (129.614 us; speedup 1.0000x reference)
//
#include <hip/hip_runtime.h>
#include <cmath>

#define DD 128
#define LOG2E 1.4426950408889634f

__device__ __forceinline__ float sigm(float x) { return 1.0f / (1.0f + __expf(-x)); }

// Fused level-1 (R16-verbatim): root passthrough + self-contained colmax0 + dense
// intersection (2 children/block, 8 waves x 8 rows) + pack epilogue + pmax store.
__global__ __launch_bounds__(512, 4)
void k_lvl1(const float* __restrict__ mu_min0, const float* __restrict__ mu_max0,
            const float* __restrict__ braw_min, const float* __restrict__ braw_max,
            const float* __restrict__ adj0, const float* __restrict__ u0,
            float* __restrict__ out,
            float2* __restrict__ mu2_1, float2* __restrict__ bb2_1,
            float4* __restrict__ pmax) {
    __shared__ __align__(8) float wsh[64][2];
    __shared__ int npres[2];
    __shared__ float4 red[8][2][64];
    __shared__ float4 cmx[8][64];
    __shared__ float4 carrA[2][64], carrB[2][64];
    const int tid = threadIdx.x;
    const int w = tid >> 6, lane = tid & 63;
    const int c0 = blockIdx.x * 2;

    if (tid < 32) {
        int i = blockIdx.x * 32 + tid;
        out[i] = mu_min0[i];
        out[8192 + i] = mu_max0[i];
        out[16384 + i] = sigm(braw_min[i]) + 1e-6f;
        out[24576 + i] = sigm(braw_max[i]) + 1e-6f;
    }

    if (tid < 128) {
        int j = w, p = lane;
        int idx = (c0 + j) * 64 + p;
        float uu = u0[idx] + 1e-10f;
        float g = -__logf(-__logf(uu) + 1e-10f);
        bool pres = (adj0[idx] + g) > 0.0f;
        wsh[p][j] = pres ? 1.0f : 1e-10f;
        unsigned long long m = __ballot(pres);
        if (lane == 0) npres[j] = (int)__popcll(m);
    }
    __syncthreads();

    const int p0 = w * 8;
    const int dbase = 2 * lane;

    float4 accB[2];
    accB[0] = make_float4(0.f, 0.f, 0.f, 0.f);
    accB[1] = make_float4(0.f, 0.f, 0.f, 0.f);
    float4 mrow[8];
    float cm_mn0 = -INFINITY, cm_mn1 = -INFINITY, cm_ng0 = -INFINITY, cm_ng1 = -INFINITY;
    #pragma unroll
    for (int z = 0; z < 8; ++z) {
        int p = p0 + z;
        float2 bmr = *(const float2*)(braw_min + p * DD + dbase);
        float2 bxr = *(const float2*)(braw_max + p * DD + dbase);
        float2 mnr = *(const float2*)(mu_min0 + p * DD + dbase);
        float2 mxr = *(const float2*)(mu_max0 + p * DD + dbase);
        float bm0 = sigm(bmr.x) + 1e-6f, bm1 = sigm(bmr.y) + 1e-6f;
        float bx0 = sigm(bxr.x) + 1e-6f, bx1 = sigm(bxr.y) + 1e-6f;
        mrow[z] = make_float4(mnr.x, mxr.x, mnr.y, mxr.y);
        cm_mn0 = fmaxf(cm_mn0, mnr.x); cm_mn1 = fmaxf(cm_mn1, mnr.y);
        cm_ng0 = fmaxf(cm_ng0, -mxr.x); cm_ng1 = fmaxf(cm_ng1, -mxr.y);
        float2 wv = *(const float2*)wsh[p];
        const float* wf = (const float*)&wv;
        #pragma unroll
        for (int j = 0; j < 2; ++j) {
            accB[j].x = fmaf(wf[j], bm0, accB[j].x);
            accB[j].y = fmaf(wf[j], bx0, accB[j].y);
            accB[j].z = fmaf(wf[j], bm1, accB[j].z);
            accB[j].w = fmaf(wf[j], bx1, accB[j].w);
        }
    }
    red[w][0][lane] = accB[0];
    red[w][1][lane] = accB[1];
    cmx[w][lane] = make_float4(cm_mn0, cm_ng0, cm_mn1, cm_ng1);
    __syncthreads();

    float bmin0, bmax0, bmin1, bmax1, rmin0, rmin1, nrmax0, nrmax1, Mm0, Mm1, Mg0, Mg1;
    const int rj = w;
    if (tid < 128) {
        float4 S = red[0][rj][lane];
        float4 M = cmx[0][lane];
        #pragma unroll
        for (int ww = 1; ww < 8; ++ww) {
            float4 t = red[ww][rj][lane];
            S.x += t.x; S.y += t.y; S.z += t.z; S.w += t.w;
            float4 m = cmx[ww][lane];
            M.x = fmaxf(M.x, m.x); M.y = fmaxf(M.y, m.y);
            M.z = fmaxf(M.z, m.z); M.w = fmaxf(M.w, m.w);
        }
        Mm0 = M.x; Mg0 = M.y; Mm1 = M.z; Mg1 = M.w;
        const float wsv = (float)npres[rj] + 1e-10f;
        bmin0 = S.x / wsv; bmax0 = S.y / wsv; bmin1 = S.z / wsv; bmax1 = S.w / wsv;
        rmin0 = 1.0f / fmaxf(bmin0, 1e-30f);
        rmin1 = 1.0f / fmaxf(bmin1, 1e-30f);
        nrmax0 = -1.0f / fmaxf(bmax0, 1e-30f);
        nrmax1 = -1.0f / fmaxf(bmax1, 1e-30f);
        float rm20 = rmin0 * LOG2E, rm21 = rmin1 * LOG2E;
        float nx20 = nrmax0 * LOG2E, nx21 = nrmax1 * LOG2E;
        carrA[rj][lane] = make_float4(rm20, rm21, nx20, nx21);
        carrB[rj][lane] = make_float4(-rm20 * Mm0, -rm21 * Mm1, nx20 * Mg0, nx21 * Mg1);
    }
    __syncthreads();

    float4 cA[2], cB[2];
    cA[0] = carrA[0][lane]; cB[0] = carrB[0][lane];
    cA[1] = carrA[1][lane]; cB[1] = carrB[1][lane];

    float4 accS[2];
    accS[0] = make_float4(0.f, 0.f, 0.f, 0.f);
    accS[1] = make_float4(0.f, 0.f, 0.f, 0.f);
    #pragma unroll
    for (int z = 0; z < 8; ++z) {
        float4 q = mrow[z];
        float2 wv = *(const float2*)wsh[p0 + z];
        const float* wf = (const float*)&wv;
        #pragma unroll
        for (int j = 0; j < 2; ++j) {
            accS[j].x = fmaf(wf[j], __builtin_amdgcn_exp2f(fmaf(q.x, cA[j].x, cB[j].x)), accS[j].x);
            accS[j].y = fmaf(wf[j], __builtin_amdgcn_exp2f(fmaf(q.y, cA[j].z, cB[j].z)), accS[j].y);
            accS[j].z = fmaf(wf[j], __builtin_amdgcn_exp2f(fmaf(q.z, cA[j].y, cB[j].y)), accS[j].z);
            accS[j].w = fmaf(wf[j], __builtin_amdgcn_exp2f(fmaf(q.w, cA[j].w, cB[j].w)), accS[j].w);
        }
    }
    red[w][0][lane] = accS[0];
    red[w][1][lane] = accS[1];
    __syncthreads();

    if (tid < 128) {
        float4 S = red[0][rj][lane];
        #pragma unroll
        for (int ww = 1; ww < 8; ++ww) {
            float4 t = red[ww][rj][lane];
            S.x += t.x; S.y += t.y; S.z += t.z; S.w += t.w;
        }
        const float S10 = fmaxf(S.x, 1e-35f);
        const float S20 = fmaxf(S.y, 1e-35f);
        const float S11 = fmaxf(S.z, 1e-35f);
        const float S21 = fmaxf(S.w, 1e-35f);
        const int cc = c0 + rj;
        const int idx = cc * DD + 2 * lane;
        float v10 = bmin0 * fmaf(rmin0, Mm0, __logf(S10));
        float v11 = bmin1 * fmaf(rmin1, Mm1, __logf(S11));
        float v20 = -bmax0 * fmaf(-nrmax0, Mg0, __logf(S20));
        float v21 = -bmax1 * fmaf(-nrmax1, Mg1, __logf(S21));
        *(float2*)(out + 32768 + idx)  = make_float2(v10, v11);
        *(float2*)(out + 98304 + idx)  = make_float2(v20, v21);
        *(float2*)(out + 163840 + idx) = make_float2(bmin0, bmin1);
        *(float2*)(out + 229376 + idx) = make_float2(bmax0, bmax1);
        *(float4*)(mu2_1 + idx) = make_float4(v10, v20, v11, v21);
        *(float4*)(bb2_1 + idx) = make_float4(bmin0, bmax0, bmin1, bmax1);
        red[0][rj][lane] = make_float4(v10, -v20, v11, -v21);
    }
    __syncthreads();
    if (tid < 64) {
        float4 a = red[0][0][tid];
        float4 b = red[0][1][tid];
        a.x = fmaxf(a.x, b.x); a.y = fmaxf(a.y, b.y);
        a.z = fmaxf(a.z, b.z); a.w = fmaxf(a.w, b.w);
        pmax[blockIdx.x * 64 + tid] = a;
    }
}

// Level-2 DENSE, TC=2: 1024 blocks x 8 waves -> 4 blocks/CU (32 waves = full
// capacity). LDS ~28 KB. Per-block traffic unchanged (streams all 512 rows);
// total L2 traffic 2x but fully L2-cached; waves 2x to overlap it.
__global__ __launch_bounds__(512, 4)
void k_level2d(const float* __restrict__ logits, const float* __restrict__ u,
               const float2* __restrict__ bb2, const float2* __restrict__ mu2,
               const float4* __restrict__ pmax,
               float* __restrict__ o_mu_min, float* __restrict__ o_mu_max,
               float* __restrict__ o_b_min, float* __restrict__ o_b_max) {
    constexpr int P = 512, TC = 2;
    __shared__ __align__(16) float wsh[P][TC];
    __shared__ int npres[TC];
    __shared__ float4 red[8][TC][64];
    __shared__ float4 cmx[8][64];      // prologue partials; later reused as carrA/carrB
    const int tid = threadIdx.x;
    const int w = tid >> 6;
    const int lane = tid & 63;
    const int c0 = blockIdx.x * TC;
    if (tid < TC) npres[tid] = 0;
    __syncthreads();

    // colmax1 prologue: wave w reduces partials [w*32, w*32+32)
    {
        float4 pm = make_float4(-INFINITY, -INFINITY, -INFINITY, -INFINITY);
        #pragma unroll
        for (int t = 0; t < 32; ++t) {
            float4 v = pmax[(w * 32 + t) * 64 + lane];
            pm.x = fmaxf(pm.x, v.x); pm.y = fmaxf(pm.y, v.y);
            pm.z = fmaxf(pm.z, v.z); pm.w = fmaxf(pm.w, v.w);
        }
        cmx[w][lane] = pm;
    }

    // pass A: 2 children x 512 rows over 512 threads (2 iterations)
    #pragma unroll
    for (int it = 0; it < TC; ++it) {
        int i = it * 512 + tid;
        int j = i >> 9;
        int p = i & 511;
        int idx = (c0 + j) * P + p;
        float uu = u[idx] + 1e-10f;
        float g = -__logf(-__logf(uu) + 1e-10f);
        bool pres = (logits[idx] + g) > 0.0f;
        wsh[p][j] = pres ? 1.0f : 1e-10f;
        unsigned long long m = __ballot(pres);
        if (lane == 0) atomicAdd(&npres[j], (int)__popcll(m));
    }
    __syncthreads();

    const unsigned lb = (unsigned)(lane << 4);
    const char* bbc = (const char*)bb2 + (unsigned)(w * 64) * 1024u + lb;
    const char* muc = (const char*)mu2 + (unsigned)(w * 64) * 1024u + lb;
    const int p0 = w * 64;

    float4 accB[TC];
    #pragma unroll
    for (int j = 0; j < TC; ++j) accB[j] = make_float4(0.f, 0.f, 0.f, 0.f);
    for (int z = 0; z < 64; z += 4) {
        float4 q0 = *(const float4*)(bbc + (unsigned)(z + 0) * 1024u);
        float4 q1 = *(const float4*)(bbc + (unsigned)(z + 1) * 1024u);
        float4 q2 = *(const float4*)(bbc + (unsigned)(z + 2) * 1024u);
        float4 q3 = *(const float4*)(bbc + (unsigned)(z + 3) * 1024u);
        float2 w0 = *(const float2*)wsh[p0 + z + 0];
        float2 w1 = *(const float2*)wsh[p0 + z + 1];
        float2 w2 = *(const float2*)wsh[p0 + z + 2];
        float2 w3 = *(const float2*)wsh[p0 + z + 3];
        const float* wf0 = (const float*)&w0;
        const float* wf1 = (const float*)&w1;
        const float* wf2 = (const float*)&w2;
        const float* wf3 = (const float*)&w3;
        #pragma unroll
        for (int j = 0; j < TC; ++j) {
            accB[j].x = fmaf(wf0[j], q0.x, fmaf(wf1[j], q1.x, fmaf(wf2[j], q2.x, fmaf(wf3[j], q3.x, accB[j].x))));
            accB[j].y = fmaf(wf0[j], q0.y, fmaf(wf1[j], q1.y, fmaf(wf2[j], q2.y, fmaf(wf3[j], q3.y, accB[j].y))));
            accB[j].z = fmaf(wf0[j], q0.z, fmaf(wf1[j], q1.z, fmaf(wf2[j], q2.z, fmaf(wf3[j], q3.z, accB[j].z))));
            accB[j].w = fmaf(wf0[j], q0.w, fmaf(wf1[j], q1.w, fmaf(wf2[j], q2.w, fmaf(wf3[j], q3.w, accB[j].w))));
        }
    }
    #pragma unroll
    for (int j = 0; j < TC; ++j) red[w][j][lane] = accB[j];
    __syncthreads();

    // reducers: constants into registers (tid<128: 2 children x 64 lanes)
    float bmin0, bmax0, bmin1, bmax1, rmin0, rmin1, nrmax0, nrmax1, Mm0, Mm1, Mg0, Mg1;
    float rm20, rm21, nx20, nx21;
    const int rj = tid >> 6;
    if (tid < 128) {
        float4 S = red[0][rj][lane];
        float4 M = cmx[0][lane];
        #pragma unroll
        for (int ww = 1; ww < 8; ++ww) {
            float4 t = red[ww][rj][lane];
            S.x += t.x; S.y += t.y; S.z += t.z; S.w += t.w;
            float4 m = cmx[ww][lane];
            M.x = fmaxf(M.x, m.x); M.y = fmaxf(M.y, m.y);
            M.z = fmaxf(M.z, m.z); M.w = fmaxf(M.w, m.w);
        }
        Mm0 = M.x; Mg0 = M.y; Mm1 = M.z; Mg1 = M.w;
        const float wsv = (float)npres[rj] + 1e-10f;
        bmin0 = S.x / wsv; bmax0 = S.y / wsv; bmin1 = S.z / wsv; bmax1 = S.w / wsv;
        rmin0 = 1.0f / fmaxf(bmin0, 1e-30f);
        rmin1 = 1.0f / fmaxf(bmin1, 1e-30f);
        nrmax0 = -1.0f / fmaxf(bmax0, 1e-30f);
        nrmax1 = -1.0f / fmaxf(bmax1, 1e-30f);
        rm20 = rmin0 * LOG2E; rm21 = rmin1 * LOG2E;
        nx20 = nrmax0 * LOG2E; nx21 = nrmax1 * LOG2E;
    }
    __syncthreads();   // all cmx reads done — safe to overwrite with carr

    float4 (*carrA)[64] = (float4(*)[64])&cmx[0];   // carrA = cmx[0..1]
    float4 (*carrB)[64] = (float4(*)[64])&cmx[2];   // carrB = cmx[2..3]
    if (tid < 128) {
        carrA[rj][lane] = make_float4(rm20, rm21, nx20, nx21);
        carrB[rj][lane] = make_float4(-rm20 * Mm0, -rm21 * Mm1, nx20 * Mg0, nx21 * Mg1);
    }
    __syncthreads();

    float4 cA[TC], cB[TC];
    #pragma unroll
    for (int j = 0; j < TC; ++j) { cA[j] = carrA[j][lane]; cB[j] = carrB[j][lane]; }

    // pass C: 4 rows per iteration; absent children skipped (wave-uniform branch)
    float4 accS[TC];
    #pragma unroll
    for (int j = 0; j < TC; ++j) accS[j] = make_float4(0.f, 0.f, 0.f, 0.f);
    for (int z = 0; z < 64; z += 4) {
        float4 q0 = *(const float4*)(muc + (unsigned)(z + 0) * 1024u);
        float4 q1 = *(const float4*)(muc + (unsigned)(z + 1) * 1024u);
        float4 q2 = *(const float4*)(muc + (unsigned)(z + 2) * 1024u);
        float4 q3 = *(const float4*)(muc + (unsigned)(z + 3) * 1024u);
        float2 w0 = *(const float2*)wsh[p0 + z + 0];
        float2 w1 = *(const float2*)wsh[p0 + z + 1];
        float2 w2 = *(const float2*)wsh[p0 + z + 2];
        float2 w3 = *(const float2*)wsh[p0 + z + 3];
        const float* wf0 = (const float*)&w0;
        const float* wf1 = (const float*)&w1;
        const float* wf2 = (const float*)&w2;
        const float* wf3 = (const float*)&w3;
        #pragma unroll
        for (int j = 0; j < TC; ++j) {
            if (wf0[j] > 0.5f) {
                accS[j].x += __builtin_amdgcn_exp2f(fmaf(q0.x, cA[j].x, cB[j].x));
                accS[j].y += __builtin_amdgcn_exp2f(fmaf(q0.y, cA[j].z, cB[j].z));
                accS[j].z += __builtin_amdgcn_exp2f(fmaf(q0.z, cA[j].y, cB[j].y));
                accS[j].w += __builtin_amdgcn_exp2f(fmaf(q0.w, cA[j].w, cB[j].w));
            }
            if (wf1[j] > 0.5f) {
                accS[j].x += __builtin_amdgcn_exp2f(fmaf(q1.x, cA[j].x, cB[j].x));
                accS[j].y += __builtin_amdgcn_exp2f(fmaf(q1.y, cA[j].z, cB[j].z));
                accS[j].z += __builtin_amdgcn_exp2f(fmaf(q1.z, cA[j].y, cB[j].y));
                accS[j].w += __builtin_amdgcn_exp2f(fmaf(q1.w, cA[j].w, cB[j].w));
            }
            if (wf2[j] > 0.5f) {
                accS[j].x += __builtin_amdgcn_exp2f(fmaf(q2.x, cA[j].x, cB[j].x));
                accS[j].y += __builtin_amdgcn_exp2f(fmaf(q2.y, cA[j].z, cB[j].z));
                accS[j].z += __builtin_amdgcn_exp2f(fmaf(q2.z, cA[j].y, cB[j].y));
                accS[j].w += __builtin_amdgcn_exp2f(fmaf(q2.w, cA[j].w, cB[j].w));
            }
            if (wf3[j] > 0.5f) {
                accS[j].x += __builtin_amdgcn_exp2f(fmaf(q3.x, cA[j].x, cB[j].x));
                accS[j].y += __builtin_amdgcn_exp2f(fmaf(q3.y, cA[j].z, cB[j].z));
                accS[j].z += __builtin_amdgcn_exp2f(fmaf(q3.z, cA[j].y, cB[j].y));
                accS[j].w += __builtin_amdgcn_exp2f(fmaf(q3.w, cA[j].w, cB[j].w));
            }
        }
    }
    #pragma unroll
    for (int j = 0; j < TC; ++j) red[w][j][lane] = accS[j];
    __syncthreads();

    if (tid < 128) {
        float4 S = red[0][rj][lane];
        #pragma unroll
        for (int ww = 1; ww < 8; ++ww) {
            float4 t = red[ww][rj][lane];
            S.x += t.x; S.y += t.y; S.z += t.z; S.w += t.w;
        }
        const float S10 = fmaxf(S.x, 1e-35f);
        const float S20 = fmaxf(S.y, 1e-35f);
        const float S11 = fmaxf(S.z, 1e-35f);
        const float S21 = fmaxf(S.w, 1e-35f);
        const int idx = (c0 + rj) * DD + 2 * lane;
        float v10 = bmin0 * fmaf(rmin0, Mm0, __logf(S10));
        float v11 = bmin1 * fmaf(rmin1, Mm1, __logf(S11));
        float v20 = -bmax0 * fmaf(-nrmax0, Mg0, __logf(S20));
        float v21 = -bmax1 * fmaf(-nrmax1, Mg1, __logf(S21));
        *(float2*)(o_mu_min + idx) = make_float2(v10, v11);
        *(float2*)(o_mu_max + idx) = make_float2(v20, v21);
        *(float2*)(o_b_min + idx)  = make_float2(bmin0, bmin1);
        *(float2*)(o_b_max + idx)  = make_float2(bmax0, bmax1);
    }
}

extern "C" void kernel_launch(void* const* d_in, const int* in_sizes, int n_in,
                              void* d_out, int out_size, void* d_ws, size_t ws_size,
                              hipStream_t stream) {
    const float* mu_min0  = (const float*)d_in[0];
    const float* mu_max0  = (const float*)d_in[1];
    const float* braw_min = (const float*)d_in[2];
    const float* braw_max = (const float*)d_in[3];
    const float* adj0     = (const float*)d_in[4];   // (512, 64)
    const float* adj1     = (const float*)d_in[5];   // (2048, 512)
    const float* u0       = (const float*)d_in[6];   // (1, 512, 64)
    const float* u1       = (const float*)d_in[7];   // (1, 2048, 512)
    float* out = (float*)d_out;
    float* ws = (float*)d_ws;

    float4* pmax  = (float4*)ws;                    // 256 blocks x 64 float4 = 256 KB
    float2* mu2_1 = (float2*)(ws + 65536);          // 512*128 float2 = 512 KB
    float2* bb2_1 = mu2_1 + 512 * DD;               // 512 KB

    // out offsets (f32): 0:mu_min0 8192:mu_max0 16384:bmin0 24576:bmax0
    // 32768:mu_min1 98304:mu_max1 163840:b_min1 229376:b_max1 (each 65536)
    // 294912:mu_min2 557056:mu_max2 819200:b_min2 1081344:b_max2 (each 262144)

    k_lvl1<<<dim3(256), dim3(512), 0, stream>>>(
        mu_min0, mu_max0, braw_min, braw_max, adj0, u0,
        out, mu2_1, bb2_1, pmax);

    k_level2d<<<dim3(1024), dim3(512), 0, stream>>>(
        adj1, u1, bb2_1, mu2_1, pmax,
        out + 294912, out + 557056, out + 819200, out + 1081344);
}

// Round 21
// 116.509 us; speedup vs baseline: 1.1125x; 1.1125x over previous
//
#include <hip/hip_runtime.h>
#include <cmath>

#define DD 128
#define LOG2E 1.4426950408889634f

__device__ __forceinline__ float sigm(float x) { return 1.0f / (1.0f + __expf(-x)); }

// Fused level-1: root passthrough slice + self-contained colmax0 + dense weighted
// intersection (2 children/block, 8 waves x 8 rows) + pack epilogue + per-block
// colmax1 partial store. 256 blocks -> full CU coverage.
__global__ __launch_bounds__(512, 4)
void k_lvl1(const float* __restrict__ mu_min0, const float* __restrict__ mu_max0,
            const float* __restrict__ braw_min, const float* __restrict__ braw_max,
            const float* __restrict__ adj0, const float* __restrict__ u0,
            float* __restrict__ out,
            float2* __restrict__ mu2_1, float2* __restrict__ bb2_1,
            float4* __restrict__ pmax) {
    __shared__ __align__(8) float wsh[64][2];
    __shared__ int npres[2];
    __shared__ float4 red[8][2][64];
    __shared__ float4 cmx[8][64];
    __shared__ float4 carrA[2][64], carrB[2][64];
    const int tid = threadIdx.x;
    const int w = tid >> 6, lane = tid & 63;
    const int c0 = blockIdx.x * 2;

    if (tid < 32) {
        int i = blockIdx.x * 32 + tid;
        out[i] = mu_min0[i];
        out[8192 + i] = mu_max0[i];
        out[16384 + i] = sigm(braw_min[i]) + 1e-6f;
        out[24576 + i] = sigm(braw_max[i]) + 1e-6f;
    }

    if (tid < 128) {
        int j = w, p = lane;
        int idx = (c0 + j) * 64 + p;
        float uu = u0[idx] + 1e-10f;
        float g = -__logf(-__logf(uu) + 1e-10f);
        bool pres = (adj0[idx] + g) > 0.0f;
        wsh[p][j] = pres ? 1.0f : 1e-10f;
        unsigned long long m = __ballot(pres);
        if (lane == 0) npres[j] = (int)__popcll(m);
    }
    __syncthreads();

    const int p0 = w * 8;
    const int dbase = 2 * lane;

    float4 accB[2];
    accB[0] = make_float4(0.f, 0.f, 0.f, 0.f);
    accB[1] = make_float4(0.f, 0.f, 0.f, 0.f);
    float4 mrow[8];
    float cm_mn0 = -INFINITY, cm_mn1 = -INFINITY, cm_ng0 = -INFINITY, cm_ng1 = -INFINITY;
    #pragma unroll
    for (int z = 0; z < 8; ++z) {
        int p = p0 + z;
        float2 bmr = *(const float2*)(braw_min + p * DD + dbase);
        float2 bxr = *(const float2*)(braw_max + p * DD + dbase);
        float2 mnr = *(const float2*)(mu_min0 + p * DD + dbase);
        float2 mxr = *(const float2*)(mu_max0 + p * DD + dbase);
        float bm0 = sigm(bmr.x) + 1e-6f, bm1 = sigm(bmr.y) + 1e-6f;
        float bx0 = sigm(bxr.x) + 1e-6f, bx1 = sigm(bxr.y) + 1e-6f;
        mrow[z] = make_float4(mnr.x, mxr.x, mnr.y, mxr.y);
        cm_mn0 = fmaxf(cm_mn0, mnr.x); cm_mn1 = fmaxf(cm_mn1, mnr.y);
        cm_ng0 = fmaxf(cm_ng0, -mxr.x); cm_ng1 = fmaxf(cm_ng1, -mxr.y);
        float2 wv = *(const float2*)wsh[p];
        const float* wf = (const float*)&wv;
        #pragma unroll
        for (int j = 0; j < 2; ++j) {
            accB[j].x = fmaf(wf[j], bm0, accB[j].x);
            accB[j].y = fmaf(wf[j], bx0, accB[j].y);
            accB[j].z = fmaf(wf[j], bm1, accB[j].z);
            accB[j].w = fmaf(wf[j], bx1, accB[j].w);
        }
    }
    red[w][0][lane] = accB[0];
    red[w][1][lane] = accB[1];
    cmx[w][lane] = make_float4(cm_mn0, cm_ng0, cm_mn1, cm_ng1);
    __syncthreads();

    float bmin0, bmax0, bmin1, bmax1, rmin0, rmin1, nrmax0, nrmax1, Mm0, Mm1, Mg0, Mg1;
    const int rj = w;
    if (tid < 128) {
        float4 S = red[0][rj][lane];
        float4 M = cmx[0][lane];
        #pragma unroll
        for (int ww = 1; ww < 8; ++ww) {
            float4 t = red[ww][rj][lane];
            S.x += t.x; S.y += t.y; S.z += t.z; S.w += t.w;
            float4 m = cmx[ww][lane];
            M.x = fmaxf(M.x, m.x); M.y = fmaxf(M.y, m.y);
            M.z = fmaxf(M.z, m.z); M.w = fmaxf(M.w, m.w);
        }
        Mm0 = M.x; Mg0 = M.y; Mm1 = M.z; Mg1 = M.w;
        const float wsv = (float)npres[rj] + 1e-10f;
        bmin0 = S.x / wsv; bmax0 = S.y / wsv; bmin1 = S.z / wsv; bmax1 = S.w / wsv;
        rmin0 = 1.0f / fmaxf(bmin0, 1e-30f);
        rmin1 = 1.0f / fmaxf(bmin1, 1e-30f);
        nrmax0 = -1.0f / fmaxf(bmax0, 1e-30f);
        nrmax1 = -1.0f / fmaxf(bmax1, 1e-30f);
        float rm20 = rmin0 * LOG2E, rm21 = rmin1 * LOG2E;
        float nx20 = nrmax0 * LOG2E, nx21 = nrmax1 * LOG2E;
        carrA[rj][lane] = make_float4(rm20, rm21, nx20, nx21);
        carrB[rj][lane] = make_float4(-rm20 * Mm0, -rm21 * Mm1, nx20 * Mg0, nx21 * Mg1);
    }
    __syncthreads();

    float4 cA[2], cB[2];
    cA[0] = carrA[0][lane]; cB[0] = carrB[0][lane];
    cA[1] = carrA[1][lane]; cB[1] = carrB[1][lane];

    float4 accS[2];
    accS[0] = make_float4(0.f, 0.f, 0.f, 0.f);
    accS[1] = make_float4(0.f, 0.f, 0.f, 0.f);
    #pragma unroll
    for (int z = 0; z < 8; ++z) {
        float4 q = mrow[z];
        float2 wv = *(const float2*)wsh[p0 + z];
        const float* wf = (const float*)&wv;
        #pragma unroll
        for (int j = 0; j < 2; ++j) {
            accS[j].x = fmaf(wf[j], __builtin_amdgcn_exp2f(fmaf(q.x, cA[j].x, cB[j].x)), accS[j].x);
            accS[j].y = fmaf(wf[j], __builtin_amdgcn_exp2f(fmaf(q.y, cA[j].z, cB[j].z)), accS[j].y);
            accS[j].z = fmaf(wf[j], __builtin_amdgcn_exp2f(fmaf(q.z, cA[j].y, cB[j].y)), accS[j].z);
            accS[j].w = fmaf(wf[j], __builtin_amdgcn_exp2f(fmaf(q.w, cA[j].w, cB[j].w)), accS[j].w);
        }
    }
    red[w][0][lane] = accS[0];
    red[w][1][lane] = accS[1];
    __syncthreads();

    if (tid < 128) {
        float4 S = red[0][rj][lane];
        #pragma unroll
        for (int ww = 1; ww < 8; ++ww) {
            float4 t = red[ww][rj][lane];
            S.x += t.x; S.y += t.y; S.z += t.z; S.w += t.w;
        }
        const float S10 = fmaxf(S.x, 1e-35f);
        const float S20 = fmaxf(S.y, 1e-35f);
        const float S11 = fmaxf(S.z, 1e-35f);
        const float S21 = fmaxf(S.w, 1e-35f);
        const int cc = c0 + rj;
        const int idx = cc * DD + 2 * lane;
        float v10 = bmin0 * fmaf(rmin0, Mm0, __logf(S10));
        float v11 = bmin1 * fmaf(rmin1, Mm1, __logf(S11));
        float v20 = -bmax0 * fmaf(-nrmax0, Mg0, __logf(S20));
        float v21 = -bmax1 * fmaf(-nrmax1, Mg1, __logf(S21));
        *(float2*)(out + 32768 + idx)  = make_float2(v10, v11);
        *(float2*)(out + 98304 + idx)  = make_float2(v20, v21);
        *(float2*)(out + 163840 + idx) = make_float2(bmin0, bmin1);
        *(float2*)(out + 229376 + idx) = make_float2(bmax0, bmax1);
        *(float4*)(mu2_1 + idx) = make_float4(v10, v20, v11, v21);
        *(float4*)(bb2_1 + idx) = make_float4(bmin0, bmax0, bmin1, bmax1);
        red[0][rj][lane] = make_float4(v10, -v20, v11, -v21);
    }
    __syncthreads();
    if (tid < 64) {
        float4 a = red[0][0][tid];
        float4 b = red[0][1][tid];
        a.x = fmaxf(a.x, b.x); a.y = fmaxf(a.y, b.y);
        a.z = fmaxf(a.z, b.z); a.w = fmaxf(a.w, b.w);
        pmax[blockIdx.x * 64 + tid] = a;
    }
}

// Level-2 DENSE (R19-verbatim, best measured): 512 threads = 8 waves; TC=4 children
// share one dense row stream; pass C issues 4 rows' loads up front; absent children
// skipped via wave-uniform branch. 512 blocks = 2 blocks/CU — measured equilibrium
// (R16 less VALU: neutral; R18 more LDS headroom: neutral; R20 more blocks: regression).
__global__ __launch_bounds__(512, 4)
void k_level2d(const float* __restrict__ logits, const float* __restrict__ u,
               const float2* __restrict__ bb2, const float2* __restrict__ mu2,
               const float4* __restrict__ pmax,
               float* __restrict__ o_mu_min, float* __restrict__ o_mu_max,
               float* __restrict__ o_b_min, float* __restrict__ o_b_max) {
    constexpr int P = 512, TC = 4;
    __shared__ __align__(16) float wsh[P][TC];
    __shared__ int npres[TC];
    __shared__ float4 red[8][TC][64];
    __shared__ float4 cmx[8][64];      // prologue partials; later reused as carrA/carrB
    const int tid = threadIdx.x;
    const int w = tid >> 6;
    const int lane = tid & 63;
    const int c0 = blockIdx.x * TC;
    if (tid < TC) npres[tid] = 0;
    __syncthreads();

    // colmax1 prologue: wave w reduces partials [w*32, w*32+32)
    {
        float4 pm = make_float4(-INFINITY, -INFINITY, -INFINITY, -INFINITY);
        #pragma unroll
        for (int t = 0; t < 32; ++t) {
            float4 v = pmax[(w * 32 + t) * 64 + lane];
            pm.x = fmaxf(pm.x, v.x); pm.y = fmaxf(pm.y, v.y);
            pm.z = fmaxf(pm.z, v.z); pm.w = fmaxf(pm.w, v.w);
        }
        cmx[w][lane] = pm;
    }

    #pragma unroll
    for (int it = 0; it < TC; ++it) {
        int idx = (c0 + it) * P + tid;
        float uu = u[idx] + 1e-10f;
        float g = -__logf(-__logf(uu) + 1e-10f);
        bool pres = (logits[idx] + g) > 0.0f;
        wsh[tid][it] = pres ? 1.0f : 1e-10f;
        unsigned long long m = __ballot(pres);
        if (lane == 0) atomicAdd(&npres[it], (int)__popcll(m));
    }
    __syncthreads();

    const unsigned lb = (unsigned)(lane << 4);
    const char* bbc = (const char*)bb2 + (unsigned)(w * 64) * 1024u + lb;
    const char* muc = (const char*)mu2 + (unsigned)(w * 64) * 1024u + lb;
    const int p0 = w * 64;

    float4 accB[TC];
    #pragma unroll
    for (int j = 0; j < TC; ++j) accB[j] = make_float4(0.f, 0.f, 0.f, 0.f);
    for (int z = 0; z < 64; z += 4) {
        float4 q0 = *(const float4*)(bbc + (unsigned)(z + 0) * 1024u);
        float4 q1 = *(const float4*)(bbc + (unsigned)(z + 1) * 1024u);
        float4 q2 = *(const float4*)(bbc + (unsigned)(z + 2) * 1024u);
        float4 q3 = *(const float4*)(bbc + (unsigned)(z + 3) * 1024u);
        float4 w0 = *(const float4*)wsh[p0 + z + 0];
        float4 w1 = *(const float4*)wsh[p0 + z + 1];
        float4 w2 = *(const float4*)wsh[p0 + z + 2];
        float4 w3 = *(const float4*)wsh[p0 + z + 3];
        const float* wf0 = (const float*)&w0;
        const float* wf1 = (const float*)&w1;
        const float* wf2 = (const float*)&w2;
        const float* wf3 = (const float*)&w3;
        #pragma unroll
        for (int j = 0; j < TC; ++j) {
            accB[j].x = fmaf(wf0[j], q0.x, fmaf(wf1[j], q1.x, fmaf(wf2[j], q2.x, fmaf(wf3[j], q3.x, accB[j].x))));
            accB[j].y = fmaf(wf0[j], q0.y, fmaf(wf1[j], q1.y, fmaf(wf2[j], q2.y, fmaf(wf3[j], q3.y, accB[j].y))));
            accB[j].z = fmaf(wf0[j], q0.z, fmaf(wf1[j], q1.z, fmaf(wf2[j], q2.z, fmaf(wf3[j], q3.z, accB[j].z))));
            accB[j].w = fmaf(wf0[j], q0.w, fmaf(wf1[j], q1.w, fmaf(wf2[j], q2.w, fmaf(wf3[j], q3.w, accB[j].w))));
        }
    }
    #pragma unroll
    for (int j = 0; j < TC; ++j) red[w][j][lane] = accB[j];
    __syncthreads();

    float bmin0, bmax0, bmin1, bmax1, rmin0, rmin1, nrmax0, nrmax1, Mm0, Mm1, Mg0, Mg1;
    float rm20, rm21, nx20, nx21;
    const int rj = tid >> 6;
    if (tid < 256) {
        float4 S = red[0][rj][lane];
        float4 M = cmx[0][lane];
        #pragma unroll
        for (int ww = 1; ww < 8; ++ww) {
            float4 t = red[ww][rj][lane];
            S.x += t.x; S.y += t.y; S.z += t.z; S.w += t.w;
            float4 m = cmx[ww][lane];
            M.x = fmaxf(M.x, m.x); M.y = fmaxf(M.y, m.y);
            M.z = fmaxf(M.z, m.z); M.w = fmaxf(M.w, m.w);
        }
        Mm0 = M.x; Mg0 = M.y; Mm1 = M.z; Mg1 = M.w;
        const float wsv = (float)npres[rj] + 1e-10f;
        bmin0 = S.x / wsv; bmax0 = S.y / wsv; bmin1 = S.z / wsv; bmax1 = S.w / wsv;
        rmin0 = 1.0f / fmaxf(bmin0, 1e-30f);
        rmin1 = 1.0f / fmaxf(bmin1, 1e-30f);
        nrmax0 = -1.0f / fmaxf(bmax0, 1e-30f);
        nrmax1 = -1.0f / fmaxf(bmax1, 1e-30f);
        rm20 = rmin0 * LOG2E; rm21 = rmin1 * LOG2E;
        nx20 = nrmax0 * LOG2E; nx21 = nrmax1 * LOG2E;
    }
    __syncthreads();   // all cmx reads done — safe to overwrite with carr

    float4 (*carrA)[64] = (float4(*)[64])&cmx[0];   // carrA = cmx[0..3]
    float4 (*carrB)[64] = (float4(*)[64])&cmx[4];   // carrB = cmx[4..7]
    if (tid < 256) {
        carrA[rj][lane] = make_float4(rm20, rm21, nx20, nx21);
        carrB[rj][lane] = make_float4(-rm20 * Mm0, -rm21 * Mm1, nx20 * Mg0, nx21 * Mg1);
    }
    __syncthreads();

    float4 cA[TC], cB[TC];
    #pragma unroll
    for (int j = 0; j < TC; ++j) { cA[j] = carrA[j][lane]; cB[j] = carrB[j][lane]; }

    float4 accS[TC];
    #pragma unroll
    for (int j = 0; j < TC; ++j) accS[j] = make_float4(0.f, 0.f, 0.f, 0.f);
    for (int z = 0; z < 64; z += 4) {
        float4 q0 = *(const float4*)(muc + (unsigned)(z + 0) * 1024u);
        float4 q1 = *(const float4*)(muc + (unsigned)(z + 1) * 1024u);
        float4 q2 = *(const float4*)(muc + (unsigned)(z + 2) * 1024u);
        float4 q3 = *(const float4*)(muc + (unsigned)(z + 3) * 1024u);
        float4 w0 = *(const float4*)wsh[p0 + z + 0];
        float4 w1 = *(const float4*)wsh[p0 + z + 1];
        float4 w2 = *(const float4*)wsh[p0 + z + 2];
        float4 w3 = *(const float4*)wsh[p0 + z + 3];
        const float* wf0 = (const float*)&w0;
        const float* wf1 = (const float*)&w1;
        const float* wf2 = (const float*)&w2;
        const float* wf3 = (const float*)&w3;
        #pragma unroll
        for (int j = 0; j < TC; ++j) {
            if (wf0[j] > 0.5f) {
                accS[j].x += __builtin_amdgcn_exp2f(fmaf(q0.x, cA[j].x, cB[j].x));
                accS[j].y += __builtin_amdgcn_exp2f(fmaf(q0.y, cA[j].z, cB[j].z));
                accS[j].z += __builtin_amdgcn_exp2f(fmaf(q0.z, cA[j].y, cB[j].y));
                accS[j].w += __builtin_amdgcn_exp2f(fmaf(q0.w, cA[j].w, cB[j].w));
            }
            if (wf1[j] > 0.5f) {
                accS[j].x += __builtin_amdgcn_exp2f(fmaf(q1.x, cA[j].x, cB[j].x));
                accS[j].y += __builtin_amdgcn_exp2f(fmaf(q1.y, cA[j].z, cB[j].z));
                accS[j].z += __builtin_amdgcn_exp2f(fmaf(q1.z, cA[j].y, cB[j].y));
                accS[j].w += __builtin_amdgcn_exp2f(fmaf(q1.w, cA[j].w, cB[j].w));
            }
            if (wf2[j] > 0.5f) {
                accS[j].x += __builtin_amdgcn_exp2f(fmaf(q2.x, cA[j].x, cB[j].x));
                accS[j].y += __builtin_amdgcn_exp2f(fmaf(q2.y, cA[j].z, cB[j].z));
                accS[j].z += __builtin_amdgcn_exp2f(fmaf(q2.z, cA[j].y, cB[j].y));
                accS[j].w += __builtin_amdgcn_exp2f(fmaf(q2.w, cA[j].w, cB[j].w));
            }
            if (wf3[j] > 0.5f) {
                accS[j].x += __builtin_amdgcn_exp2f(fmaf(q3.x, cA[j].x, cB[j].x));
                accS[j].y += __builtin_amdgcn_exp2f(fmaf(q3.y, cA[j].z, cB[j].z));
                accS[j].z += __builtin_amdgcn_exp2f(fmaf(q3.z, cA[j].y, cB[j].y));
                accS[j].w += __builtin_amdgcn_exp2f(fmaf(q3.w, cA[j].w, cB[j].w));
            }
        }
    }
    #pragma unroll
    for (int j = 0; j < TC; ++j) red[w][j][lane] = accS[j];
    __syncthreads();

    if (tid < 256) {
        float4 S = red[0][rj][lane];
        #pragma unroll
        for (int ww = 1; ww < 8; ++ww) {
            float4 t = red[ww][rj][lane];
            S.x += t.x; S.y += t.y; S.z += t.z; S.w += t.w;
        }
        const float S10 = fmaxf(S.x, 1e-35f);
        const float S20 = fmaxf(S.y, 1e-35f);
        const float S11 = fmaxf(S.z, 1e-35f);
        const float S21 = fmaxf(S.w, 1e-35f);
        const int idx = (c0 + rj) * DD + 2 * lane;
        float v10 = bmin0 * fmaf(rmin0, Mm0, __logf(S10));
        float v11 = bmin1 * fmaf(rmin1, Mm1, __logf(S11));
        float v20 = -bmax0 * fmaf(-nrmax0, Mg0, __logf(S20));
        float v21 = -bmax1 * fmaf(-nrmax1, Mg1, __logf(S21));
        *(float2*)(o_mu_min + idx) = make_float2(v10, v11);
        *(float2*)(o_mu_max + idx) = make_float2(v20, v21);
        *(float2*)(o_b_min + idx)  = make_float2(bmin0, bmin1);
        *(float2*)(o_b_max + idx)  = make_float2(bmax0, bmax1);
    }
}

extern "C" void kernel_launch(void* const* d_in, const int* in_sizes, int n_in,
                              void* d_out, int out_size, void* d_ws, size_t ws_size,
                              hipStream_t stream) {
    const float* mu_min0  = (const float*)d_in[0];
    const float* mu_max0  = (const float*)d_in[1];
    const float* braw_min = (const float*)d_in[2];
    const float* braw_max = (const float*)d_in[3];
    const float* adj0     = (const float*)d_in[4];   // (512, 64)
    const float* adj1     = (const float*)d_in[5];   // (2048, 512)
    const float* u0       = (const float*)d_in[6];   // (1, 512, 64)
    const float* u1       = (const float*)d_in[7];   // (1, 2048, 512)
    float* out = (float*)d_out;
    float* ws = (float*)d_ws;

    float4* pmax  = (float4*)ws;                    // 256 blocks x 64 float4 = 256 KB
    float2* mu2_1 = (float2*)(ws + 65536);          // 512*128 float2 = 512 KB
    float2* bb2_1 = mu2_1 + 512 * DD;               // 512 KB

    // out offsets (f32): 0:mu_min0 8192:mu_max0 16384:bmin0 24576:bmax0
    // 32768:mu_min1 98304:mu_max1 163840:b_min1 229376:b_max1 (each 65536)
    // 294912:mu_min2 557056:mu_max2 819200:b_min2 1081344:b_max2 (each 262144)

    k_lvl1<<<dim3(256), dim3(512), 0, stream>>>(
        mu_min0, mu_max0, braw_min, braw_max, adj0, u0,
        out, mu2_1, bb2_1, pmax);

    k_level2d<<<dim3(512), dim3(512), 0, stream>>>(
        adj1, u1, bb2_1, mu2_1, pmax,
        out + 294912, out + 557056, out + 819200, out + 1081344);
}